// Round 5
// baseline (135.001 us; speedup 1.0000x reference)
//
#include <hip/hip_runtime.h>
#include <stdint.h>

// ColBERT MaxSim on MI355X (gfx950), round 5.
// scores[b,c] = sum_n max_s dot(qs[b,n,:], ps[c,s,:])
// qs: (64, 32, 128) f32, ps: (64, 1024, 128) f32, out: (64, 64) f32.
//
// R3/R4 (55 us, identical despite 6x FETCH difference): NOT memory-bound.
// VGPR_Count=116 proved qf[4][8] (128 regs) was never register-resident —
// compiler rematerialized Q-fragment loads inside the K-loop (32 extra global
// loads + addressing per tile) -> wave-serial latency chain binds at 24%
// MfmaUtil. R5: Q staged in LDS in MFMA-fragment order (frag[b][k][lane],
// 16 B/lane contiguous, ds_read_b128 with immediate offsets, conflict-free),
// k-major MFMA (4 independent acc chains), P register double-buffer kept.

typedef __bf16 bf16x8 __attribute__((ext_vector_type(8)));
typedef float floatx16 __attribute__((ext_vector_type(16)));

#define QS_N (64u * 32u * 128u)    // 262144
#define PS_N (64u * 1024u * 128u)  // 8388608

__device__ inline unsigned short f2bf(float f) {
  union { float f; uint32_t u; } x{f};
  uint32_t r = (x.u + 0x7FFFu + ((x.u >> 16) & 1u)) >> 16;  // RNE
  return (unsigned short)r;
}

// Fused cvt: first QS_N/4 float4s from qs, rest from ps; qsb = ws, psb = ws + QS_N.
__global__ __launch_bounds__(256) void cvt_kernel(const float* __restrict__ qs,
                                                  const float* __restrict__ ps,
                                                  ushort* __restrict__ outb) {
  const int nq4 = QS_N / 4;
  const int n4 = (QS_N + PS_N) / 4;
  int i = blockIdx.x * 256 + threadIdx.x;
  if (i >= n4) return;
  float4 f;
  if (i < nq4) {
    f = ((const float4*)qs)[i];
  } else {
    f = ((const float4*)ps)[i - nq4];
  }
  ushort4 o;
  o.x = f2bf(f.x); o.y = f2bf(f.y); o.z = f2bf(f.z); o.w = f2bf(f.w);
  ((ushort4*)outb)[i] = o;
}

union FragU { uint4 u; bf16x8 v; };

__device__ inline bf16x8 load_frag_bf16(const ushort* p) {
  FragU f;
  f.u = *(const uint4*)p;
  return f.v;
}

__device__ inline bf16x8 load_frag_f32(const float* p) {
  float4 a = *(const float4*)p;
  float4 b = *(const float4*)(p + 4);
  union { ushort s[8]; bf16x8 v; } r;
  r.s[0] = f2bf(a.x); r.s[1] = f2bf(a.y); r.s[2] = f2bf(a.z); r.s[3] = f2bf(a.w);
  r.s[4] = f2bf(b.x); r.s[5] = f2bf(b.y); r.s[6] = f2bf(b.z); r.s[7] = f2bf(b.w);
  return r.v;
}

template <bool PRECVT>
__device__ inline bf16x8 load_a(const void* p, int off) {
  return PRECVT ? load_frag_bf16((const ushort*)p + off)
                : load_frag_f32((const float*)p + off);
}

__device__ inline float rmax16(const floatx16& a) {
  float m0 = fmaxf(fmaxf(a[0], a[1]), fmaxf(a[2], a[3]));
  float m1 = fmaxf(fmaxf(a[4], a[5]), fmaxf(a[6], a[7]));
  float m2 = fmaxf(fmaxf(a[8], a[9]), fmaxf(a[10], a[11]));
  float m3 = fmaxf(fmaxf(a[12], a[13]), fmaxf(a[14], a[15]));
  return fmaxf(fmaxf(m0, m1), fmaxf(m2, m3));
}

#define ZERO16 {0, 0, 0, 0, 0, 0, 0, 0, 0, 0, 0, 0, 0, 0, 0, 0}

template <bool PRECVT>
__global__ __launch_bounds__(256) void maxsim_kernel(const void* __restrict__ qsv,
                                                     const void* __restrict__ psv,
                                                     float* __restrict__ out) {
  const int lane = threadIdx.x & 63;
  const int wave = threadIdx.x >> 6;

  // XCD-aware swizzle (kept from R4: P_c stays L2-resident; heuristic only).
  const int xcd = blockIdx.x & 7;
  const int slot = blockIdx.x >> 3;
  const int c = xcd * 8 + (slot >> 4);
  const int bg = slot & 15;
  const int b0 = bg * 4;
  const int row = lane & 31;         // A: s-row in tile; B frag: query token n
  const int koff = (lane >> 5) * 8;  // K-half selector

  // Q staged in MFMA B-fragment order: frag id = (b*8 + k)*64 + lane, 16 B each.
  // Read side: ds_read_b128, base = lane*16, imm offset = (b*8+k)*1024.
  __shared__ ushort lds_q[4 * 8 * 64 * 8];  // 32 KiB
  {
    uint4* dst = (uint4*)lds_q;
#pragma unroll
    for (int i = 0; i < 8; ++i) {
      const int id = threadIdx.x + i * 256;  // 0..2047
      const int l = id & 63;
      const int k = (id >> 6) & 7;
      const int b = id >> 9;
      const int goff = ((b0 + b) * 32 + (l & 31)) * 128 + k * 16 + (l >> 5) * 8;
      uint4 v;
      if (PRECVT) {
        v = *(const uint4*)((const ushort*)qsv + goff);
      } else {
        const float* q = (const float*)qsv + goff;
        float4 x = *(const float4*)q;
        float4 y = *(const float4*)(q + 4);
        union { ushort s[8]; uint4 u; } r;
        r.s[0] = f2bf(x.x); r.s[1] = f2bf(x.y); r.s[2] = f2bf(x.z); r.s[3] = f2bf(x.w);
        r.s[4] = f2bf(y.x); r.s[5] = f2bf(y.y); r.s[6] = f2bf(y.z); r.s[7] = f2bf(y.w);
        v = r.u;
      }
      dst[id] = v;  // consecutive threads -> consecutive 16 B: conflict-free
    }
  }
  __syncthreads();

  const ushort* lq = lds_q + lane * 8;  // element base for this lane's fragments

  // Wave covers s in [wave*256, wave*256+256): 8 tiles of 32 doc tokens.
  const int pbase = (c * 1024 + wave * 256 + row) * 128 + koff;

  // Issue tile-0 A prefetch first.
  bf16x8 a0[8], a1[8];
#pragma unroll
  for (int k = 0; k < 8; ++k) a0[k] = load_a<PRECVT>(psv, pbase + k * 16);

  float vmax[4];
#pragma unroll
  for (int b = 0; b < 4; ++b) vmax[b] = -3.4e38f;

#pragma unroll 1
  for (int t = 0; t < 8; t += 2) {
    // Prefetch tile t+1 into a1; compute tile t from a0.
#pragma unroll
    for (int k = 0; k < 8; ++k)
      a1[k] = load_a<PRECVT>(psv, pbase + (t + 1) * 4096 + k * 16);
    {
      floatx16 acc0 = ZERO16, acc1 = ZERO16, acc2 = ZERO16, acc3 = ZERO16;
#pragma unroll
      for (int k = 0; k < 8; ++k) {
        bf16x8 q0 = *(const bf16x8*)(lq + (0 * 8 + k) * 512);
        bf16x8 q1 = *(const bf16x8*)(lq + (1 * 8 + k) * 512);
        bf16x8 q2 = *(const bf16x8*)(lq + (2 * 8 + k) * 512);
        bf16x8 q3 = *(const bf16x8*)(lq + (3 * 8 + k) * 512);
        acc0 = __builtin_amdgcn_mfma_f32_32x32x16_bf16(a0[k], q0, acc0, 0, 0, 0);
        acc1 = __builtin_amdgcn_mfma_f32_32x32x16_bf16(a0[k], q1, acc1, 0, 0, 0);
        acc2 = __builtin_amdgcn_mfma_f32_32x32x16_bf16(a0[k], q2, acc2, 0, 0, 0);
        acc3 = __builtin_amdgcn_mfma_f32_32x32x16_bf16(a0[k], q3, acc3, 0, 0, 0);
      }
      vmax[0] = fmaxf(vmax[0], rmax16(acc0));
      vmax[1] = fmaxf(vmax[1], rmax16(acc1));
      vmax[2] = fmaxf(vmax[2], rmax16(acc2));
      vmax[3] = fmaxf(vmax[3], rmax16(acc3));
    }
    // Prefetch tile t+2 into a0 (wrap on last iter; harmless re-read).
    int t2 = t + 2;
    if (t2 > 7) t2 = 0;
#pragma unroll
    for (int k = 0; k < 8; ++k)
      a0[k] = load_a<PRECVT>(psv, pbase + t2 * 4096 + k * 16);
    // Compute tile t+1 from a1.
    {
      floatx16 acc0 = ZERO16, acc1 = ZERO16, acc2 = ZERO16, acc3 = ZERO16;
#pragma unroll
      for (int k = 0; k < 8; ++k) {
        bf16x8 q0 = *(const bf16x8*)(lq + (0 * 8 + k) * 512);
        bf16x8 q1 = *(const bf16x8*)(lq + (1 * 8 + k) * 512);
        bf16x8 q2 = *(const bf16x8*)(lq + (2 * 8 + k) * 512);
        bf16x8 q3 = *(const bf16x8*)(lq + (3 * 8 + k) * 512);
        acc0 = __builtin_amdgcn_mfma_f32_32x32x16_bf16(a1[k], q0, acc0, 0, 0, 0);
        acc1 = __builtin_amdgcn_mfma_f32_32x32x16_bf16(a1[k], q1, acc1, 0, 0, 0);
        acc2 = __builtin_amdgcn_mfma_f32_32x32x16_bf16(a1[k], q2, acc2, 0, 0, 0);
        acc3 = __builtin_amdgcn_mfma_f32_32x32x16_bf16(a1[k], q3, acc3, 0, 0, 0);
      }
      vmax[0] = fmaxf(vmax[0], rmax16(acc0));
      vmax[1] = fmaxf(vmax[1], rmax16(acc1));
      vmax[2] = fmaxf(vmax[2], rmax16(acc2));
      vmax[3] = fmaxf(vmax[3], rmax16(acc3));
    }
  }

  // Lanes l and l^32 hold complementary row-halves of the same query-token col.
#pragma unroll
  for (int b = 0; b < 4; ++b) vmax[b] = fmaxf(vmax[b], __shfl_xor(vmax[b], 32, 64));

  // Cross-wave max, then sum over the 32 query tokens.
  __shared__ float red[4][4][32];  // [wave][b][n]
  if (lane < 32) {
#pragma unroll
    for (int b = 0; b < 4; ++b) red[wave][b][lane] = vmax[b];
  }
  __syncthreads();
  if (threadIdx.x < 128) {
    const int b = threadIdx.x >> 5;
    const int n = threadIdx.x & 31;
    float m = fmaxf(fmaxf(red[0][b][n], red[1][b][n]), fmaxf(red[2][b][n], red[3][b][n]));
#pragma unroll
    for (int o = 16; o > 0; o >>= 1) m += __shfl_xor(m, o, 32);
    if (n == 0) out[(b0 + b) * 64 + c] = m;
  }
}

extern "C" void kernel_launch(void* const* d_in, const int* in_sizes, int n_in,
                              void* d_out, int out_size, void* d_ws, size_t ws_size,
                              hipStream_t stream) {
  const float* qs = (const float*)d_in[0];
  const float* ps = (const float*)d_in[1];
  float* out = (float*)d_out;

  const size_t need = (QS_N + PS_N) * sizeof(ushort);  // 16.5 MiB

  if (ws_size >= need) {
    ushort* wsb = (ushort*)d_ws;
    const int n4 = (int)((QS_N + PS_N) / 4);
    cvt_kernel<<<(n4 + 255) / 256, 256, 0, stream>>>(qs, ps, wsb);
    maxsim_kernel<true><<<dim3(64 * 16), dim3(256), 0, stream>>>(wsb, wsb + QS_N, out);
  } else {
    maxsim_kernel<false><<<dim3(64 * 16), dim3(256), 0, stream>>>(qs, ps, out);
  }
}

// Round 6
// 115.353 us; speedup vs baseline: 1.1703x; 1.1703x over previous
//
#include <hip/hip_runtime.h>
#include <stdint.h>

// ColBERT MaxSim on MI355X (gfx950), round 6.
// scores[b,c] = sum_n max_s dot(qs[b,n,:], ps[c,s,:])
// qs: (64, 32, 128) f32, ps: (64, 1024, 128) f32, out: (64, 64) f32.
//
// R3/R4/R5 all ~55-62 us with MfmaUtil ~22%: structurally FETCH-bound, not
// latency-bound. Per CU: 4 MFMA pipes (32x32x16 = 8 cyc each) vs ONE LDS/L1
// port (~128 B/cyc = 1 KB per 8 cyc). One 1 KB operand fetch per MFMA ->
// fetch pipe 4x oversubscribed -> 22% MfmaUtil. Fix: Q fragments truly
// register-resident (qf[4][8] = 128 VGPRs, read from LDS ONCE before the
// s-loop), so per-MFMA fetch drops to 0.25 KB (A-frags only, 4-way b-reuse).
// R3's version of this failed because the compiler targets 4 waves/SIMD by
// default and sank the loads (VGPR=116); R2 crashed because a ~290-reg live
// set was forced under a 256 cap (spill). Here: live set = qf 128 + a0/a1 64
// + 2 acc chains 32 = 224 < 256, declared __launch_bounds__(256, 2).

typedef __bf16 bf16x8 __attribute__((ext_vector_type(8)));
typedef float floatx16 __attribute__((ext_vector_type(16)));

#define QS_N (64u * 32u * 128u)    // 262144
#define PS_N (64u * 1024u * 128u)  // 8388608

__device__ inline unsigned short f2bf(float f) {
  union { float f; uint32_t u; } x{f};
  uint32_t r = (x.u + 0x7FFFu + ((x.u >> 16) & 1u)) >> 16;  // RNE
  return (unsigned short)r;
}

// Fused cvt: first QS_N/4 float4s from qs, rest from ps; qsb = ws, psb = ws + QS_N.
__global__ __launch_bounds__(256) void cvt_kernel(const float* __restrict__ qs,
                                                  const float* __restrict__ ps,
                                                  ushort* __restrict__ outb) {
  const int nq4 = QS_N / 4;
  const int n4 = (QS_N + PS_N) / 4;
  int i = blockIdx.x * 256 + threadIdx.x;
  if (i >= n4) return;
  float4 f;
  if (i < nq4) {
    f = ((const float4*)qs)[i];
  } else {
    f = ((const float4*)ps)[i - nq4];
  }
  ushort4 o;
  o.x = f2bf(f.x); o.y = f2bf(f.y); o.z = f2bf(f.z); o.w = f2bf(f.w);
  ((ushort4*)outb)[i] = o;
}

union FragU { uint4 u; bf16x8 v; };

__device__ inline bf16x8 load_frag_bf16(const ushort* p) {
  FragU f;
  f.u = *(const uint4*)p;
  return f.v;
}

__device__ inline bf16x8 load_frag_f32(const float* p) {
  float4 a = *(const float4*)p;
  float4 b = *(const float4*)(p + 4);
  union { ushort s[8]; bf16x8 v; } r;
  r.s[0] = f2bf(a.x); r.s[1] = f2bf(a.y); r.s[2] = f2bf(a.z); r.s[3] = f2bf(a.w);
  r.s[4] = f2bf(b.x); r.s[5] = f2bf(b.y); r.s[6] = f2bf(b.z); r.s[7] = f2bf(b.w);
  return r.v;
}

template <bool PRECVT>
__device__ inline bf16x8 load_a(const void* p, int off) {
  return PRECVT ? load_frag_bf16((const ushort*)p + off)
                : load_frag_f32((const float*)p + off);
}

__device__ inline float rmax16(const floatx16& a) {
  float m0 = fmaxf(fmaxf(a[0], a[1]), fmaxf(a[2], a[3]));
  float m1 = fmaxf(fmaxf(a[4], a[5]), fmaxf(a[6], a[7]));
  float m2 = fmaxf(fmaxf(a[8], a[9]), fmaxf(a[10], a[11]));
  float m3 = fmaxf(fmaxf(a[12], a[13]), fmaxf(a[14], a[15]));
  return fmaxf(fmaxf(m0, m1), fmaxf(m2, m3));
}

#define ZERO16 {0, 0, 0, 0, 0, 0, 0, 0, 0, 0, 0, 0, 0, 0, 0, 0}

// Compute one 32-doc-token tile against all 4 query blocks.
// Two acc chains live at a time (b pairs) -> 32 acc VGPRs.
#define TILE_COMPUTE(ABUF)                                                     \
  {                                                                            \
    floatx16 acc0 = ZERO16, acc1 = ZERO16;                                     \
    _Pragma("unroll") for (int k = 0; k < 8; ++k) {                            \
      acc0 = __builtin_amdgcn_mfma_f32_32x32x16_bf16(ABUF[k], qf[0][k], acc0, 0, 0, 0); \
      acc1 = __builtin_amdgcn_mfma_f32_32x32x16_bf16(ABUF[k], qf[1][k], acc1, 0, 0, 0); \
    }                                                                          \
    vmax[0] = fmaxf(vmax[0], rmax16(acc0));                                    \
    vmax[1] = fmaxf(vmax[1], rmax16(acc1));                                    \
    floatx16 acc2 = ZERO16, acc3 = ZERO16;                                     \
    _Pragma("unroll") for (int k = 0; k < 8; ++k) {                            \
      acc2 = __builtin_amdgcn_mfma_f32_32x32x16_bf16(ABUF[k], qf[2][k], acc2, 0, 0, 0); \
      acc3 = __builtin_amdgcn_mfma_f32_32x32x16_bf16(ABUF[k], qf[3][k], acc3, 0, 0, 0); \
    }                                                                          \
    vmax[2] = fmaxf(vmax[2], rmax16(acc2));                                    \
    vmax[3] = fmaxf(vmax[3], rmax16(acc3));                                    \
  }

template <bool PRECVT>
__global__ __launch_bounds__(256, 2) void maxsim_kernel(const void* __restrict__ qsv,
                                                        const void* __restrict__ psv,
                                                        float* __restrict__ out) {
  const int lane = threadIdx.x & 63;
  const int wave = threadIdx.x >> 6;

  // XCD-aware swizzle (R4: keeps P_c L2-resident, FETCH 66 -> 10 MB).
  const int xcd = blockIdx.x & 7;
  const int slot = blockIdx.x >> 3;
  const int c = xcd * 8 + (slot >> 4);
  const int bg = slot & 15;
  const int b0 = bg * 4;
  const int row = lane & 31;         // A: s-row in tile; B frag: query token n
  const int koff = (lane >> 5) * 8;  // K-half selector

  // Stage Q in MFMA B-fragment order: frag id = (b*8 + k)*64 + lane, 16 B each.
  __shared__ ushort lds_q[4 * 8 * 64 * 8];  // 32 KiB
  {
    uint4* dst = (uint4*)lds_q;
#pragma unroll
    for (int i = 0; i < 8; ++i) {
      const int id = threadIdx.x + i * 256;  // 0..2047
      const int l = id & 63;
      const int k = (id >> 6) & 7;
      const int b = id >> 9;
      const int goff = ((b0 + b) * 32 + (l & 31)) * 128 + k * 16 + (l >> 5) * 8;
      uint4 v;
      if (PRECVT) {
        v = *(const uint4*)((const ushort*)qsv + goff);
      } else {
        const float* q = (const float*)qsv + goff;
        float4 x = *(const float4*)q;
        float4 y = *(const float4*)(q + 4);
        union { ushort s[8]; uint4 u; } r;
        r.s[0] = f2bf(x.x); r.s[1] = f2bf(x.y); r.s[2] = f2bf(x.z); r.s[3] = f2bf(x.w);
        r.s[4] = f2bf(y.x); r.s[5] = f2bf(y.y); r.s[6] = f2bf(y.z); r.s[7] = f2bf(y.w);
        v = r.u;
      }
      dst[id] = v;  // consecutive threads -> consecutive 16 B: conflict-free
    }
  }
  __syncthreads();

  // Pull ALL Q fragments into registers ONCE (32 x ds_read_b128, 128 VGPRs).
  // B-operand layout: B[n = lane&31][k = (lane>>5)*8 + j].
  const ushort* lq = lds_q + lane * 8;
  bf16x8 qf[4][8];
#pragma unroll
  for (int b = 0; b < 4; ++b)
#pragma unroll
    for (int k = 0; k < 8; ++k)
      qf[b][k] = *(const bf16x8*)(lq + (b * 8 + k) * 512);

  // Wave covers s in [wave*256, wave*256+256): 8 tiles of 32 doc tokens.
  const int pbase = (c * 1024 + wave * 256 + row) * 128 + koff;

  // Tile-0 A prefetch.
  bf16x8 a0[8], a1[8];
#pragma unroll
  for (int k = 0; k < 8; ++k) a0[k] = load_a<PRECVT>(psv, pbase + k * 16);

  float vmax[4];
#pragma unroll
  for (int b = 0; b < 4; ++b) vmax[b] = -3.4e38f;

#pragma unroll 1
  for (int t = 0; t < 8; t += 2) {
    // Prefetch tile t+1 into a1; compute tile t from a0.
#pragma unroll
    for (int k = 0; k < 8; ++k)
      a1[k] = load_a<PRECVT>(psv, pbase + (t + 1) * 4096 + k * 16);
    TILE_COMPUTE(a0)
    // Prefetch tile t+2 into a0 (wrap on last iter; harmless re-read).
    int t2 = t + 2;
    if (t2 > 7) t2 = 0;
#pragma unroll
    for (int k = 0; k < 8; ++k)
      a0[k] = load_a<PRECVT>(psv, pbase + t2 * 4096 + k * 16);
    // Compute tile t+1 from a1.
    TILE_COMPUTE(a1)
  }

  // Lanes l and l^32 hold complementary row-halves of the same query-token col.
#pragma unroll
  for (int b = 0; b < 4; ++b) vmax[b] = fmaxf(vmax[b], __shfl_xor(vmax[b], 32, 64));

  // Cross-wave max, then sum over the 32 query tokens.
  __shared__ float red[4][4][32];  // [wave][b][n]
  if (lane < 32) {
#pragma unroll
    for (int b = 0; b < 4; ++b) red[wave][b][lane] = vmax[b];
  }
  __syncthreads();
  if (threadIdx.x < 128) {
    const int b = threadIdx.x >> 5;
    const int n = threadIdx.x & 31;
    float m = fmaxf(fmaxf(red[0][b][n], red[1][b][n]), fmaxf(red[2][b][n], red[3][b][n]));
#pragma unroll
    for (int o = 16; o > 0; o >>= 1) m += __shfl_xor(m, o, 32);
    if (n == 0) out[(b0 + b) * 64 + c] = m;
  }
}

extern "C" void kernel_launch(void* const* d_in, const int* in_sizes, int n_in,
                              void* d_out, int out_size, void* d_ws, size_t ws_size,
                              hipStream_t stream) {
  const float* qs = (const float*)d_in[0];
  const float* ps = (const float*)d_in[1];
  float* out = (float*)d_out;

  const size_t need = (QS_N + PS_N) * sizeof(ushort);  // 16.5 MiB

  if (ws_size >= need) {
    ushort* wsb = (ushort*)d_ws;
    const int n4 = (int)((QS_N + PS_N) / 4);
    cvt_kernel<<<(n4 + 255) / 256, 256, 0, stream>>>(qs, ps, wsb);
    maxsim_kernel<true><<<dim3(64 * 16), dim3(256), 0, stream>>>(wsb, wsb + QS_N, out);
  } else {
    maxsim_kernel<false><<<dim3(64 * 16), dim3(256), 0, stream>>>(qs, ps, out);
  }
}